// Round 2
// baseline (214.997 us; speedup 1.0000x reference)
//
#include <hip/hip_runtime.h>
#include <math.h>

#define EPS_F 1e-7f

constexpr int Bc = 32, Tc = 8192, Kc = 16;
constexpr int ROWS   = Bc * Tc;            // 262144
constexpr int BLOCK  = 256;
constexpr int NITEM4 = ROWS * 4;           // 1048576 vec4 items
constexpr int NTILE  = NITEM4 / BLOCK;     // 4096 tiles of 256 vec4 items
constexpr int NBLK   = 512;                // ~2 sequential blocks per CU
constexpr int TPB    = NTILE / NBLK;       // 8 tiles per block (chunked)

// ---- per-wave, per-buffer LDS layout (bytes). Each wave stages ONLY what it
// consumes (incl. its own copy of the 64 row scalars) -> no cross-wave deps,
// no __syncthreads in the main loop.
constexpr int W_OCID = 0;
constexpr int W_OCAN = 1024;
constexpr int W_OFIR = 2048;
constexpr int W_OVAL = 3072;
constexpr int W_CID  = 4096;
constexpr int W_LIVE = 5120;
constexpr int W_TRIG = 6144;
constexpr int W_VALP = 7168;
constexpr int W_CLOG = 8192;               // 3 KB
constexpr int W_WSC  = 11264;              // 256 B: all 64 rows of the tile
constexpr int W_OSW  = 11520;              // 256 B
constexpr int BUFB   = 11776;              // bytes per buffer per wave (16B-aligned)
constexpr int DEPTH  = 2;                  // double buffer
constexpr int SMEM_BYTES = 4 * DEPTH * BUFB;   // 94208 -> 1 block/CU

typedef unsigned long long u64;

__device__ __forceinline__ u64 shflx64(u64 v, int m) {
  unsigned lo = __shfl_xor((unsigned)v, m, 64);
  unsigned hi = __shfl_xor((unsigned)(v >> 32), m, 64);
  return ((u64)hi << 32) | lo;
}

// Async global->LDS DMA. LDS dest is WAVE-UNIFORM base; HW scatters lane i's
// data to base + i*size [m104/m108]. No destination VGPRs -> no register-burst
// serialization.
__device__ __forceinline__ void dma16(void* lds, const void* g) {
  __builtin_amdgcn_global_load_lds(
      (const __attribute__((address_space(1))) void*)g,
      (__attribute__((address_space(3))) void*)lds, 16, 0, 0);
}
__device__ __forceinline__ void dma4(void* lds, const void* g) {
  __builtin_amdgcn_global_load_lds(
      (const __attribute__((address_space(1))) void*)g,
      (__attribute__((address_space(3))) void*)lds, 4, 0, 0);
}

// Counted-vmcnt wait: asm "memory" clobber keeps the LDS reads below it;
// sched_barrier(0) guards against hoisting (guide rule #18).
#define WAITCNT_VM(N)                                                      \
  do {                                                                     \
    asm volatile("s_waitcnt vmcnt(" #N ")" ::: "memory");                  \
    __builtin_amdgcn_sched_barrier(0);                                     \
  } while (0)

// Stage one 256-item tile's wave-share: exactly 13 vmem ops.
__device__ __forceinline__ void stage_tile(
    char* sb, int gt, int w, int lane,
    const char* trig, const char* valp, const char* clog, const char* wscore,
    const char* live, const char* cid, const char* ofire, const char* ocan,
    const char* ovalid, const char* oshw, const char* ocid)
{
  const size_t o16 = (size_t)(gt * 256 + w * 64 + lane) * 16;
  dma16(sb + W_OCID, ocid   + o16);
  dma16(sb + W_OCAN, ocan   + o16);
  dma16(sb + W_OFIR, ofire  + o16);
  dma16(sb + W_OVAL, ovalid + o16);
  dma16(sb + W_CID,  cid    + o16);
  dma16(sb + W_LIVE, live   + o16);
  dma16(sb + W_TRIG, trig   + o16);
  dma16(sb + W_VALP, valp   + o16);
  // clog: this wave's 3KB chunk as 3 contiguous 1KB DMAs
  const char* gc = clog + (size_t)(gt * 256 + w * 64) * 48;
  dma16(sb + W_CLOG + 0,    gc + 0    + lane * 16);
  dma16(sb + W_CLOG + 1024, gc + 1024 + lane * 16);
  dma16(sb + W_CLOG + 2048, gc + 2048 + lane * 16);
  // row scalars: each wave stages its own full copy of the tile's 64 rows
  // (redundant x4, +1.5KB/tile traffic, L2-absorbed; keeps waves independent)
  const size_t ro = (size_t)(gt * 64 + lane) * 4;
  dma4(sb + W_WSC, wscore + ro);
  dma4(sb + W_OSW, oshw   + ro);
}

__global__ __launch_bounds__(BLOCK) void loss_main(
    const float* __restrict__ trig,
    const float* __restrict__ valp,
    const float* __restrict__ clog,
    const float* __restrict__ wscore,
    const int*   __restrict__ live,
    const int*   __restrict__ cid,
    const float* __restrict__ ofire,
    const int*   __restrict__ ocan,
    const float* __restrict__ ovalid,
    const float* __restrict__ oshw,
    const int*   __restrict__ ocid,
    float* __restrict__ part)            // [NBLK][6]
{
  __shared__ __align__(16) char smem[SMEM_BYTES];

  const int tid  = threadIdx.x;
  const int lane = tid & 63;
  const int w    = tid >> 6;                 // wave id 0..3
  const int gt0  = blockIdx.x * TPB;         // first tile of this block

  const char* trig_b   = (const char*)trig;
  const char* valp_b   = (const char*)valp;
  const char* clog_b   = (const char*)clog;
  const char* wscore_b = (const char*)wscore;
  const char* live_b   = (const char*)live;
  const char* cid_b    = (const char*)cid;
  const char* ofire_b  = (const char*)ofire;
  const char* ocan_b   = (const char*)ocan;
  const char* ovalid_b = (const char*)ovalid;
  const char* oshw_b   = (const char*)oshw;
  const char* ocid_b   = (const char*)ocid;

  char* wb = smem + (size_t)w * (DEPTH * BUFB);   // this wave's buffer pair

  // ---- prologue: stage tile 0 into buf 0 (13 vmem ops in flight)
  stage_tile(wb, gt0, w, lane, trig_b, valp_b, clog_b, wscore_b, live_b,
             cid_b, ofire_b, ocan_b, ovalid_b, oshw_b, ocid_b);

  float a0 = 0.f, a1 = 0.f, a2 = 0.f, a3 = 0.f, a4 = 0.f, a5 = 0.f;

  for (int t = 0; t < TPB; ++t) {
    char* sb = wb + (t & 1) * BUFB;

    if (t + 1 < TPB) {
      // WAR guard: previous compute's ds_reads fully retired before we
      // overwrite its buffer (normally already drained; near-free).
      asm volatile("s_waitcnt lgkmcnt(0)" ::: "memory");
      stage_tile(wb + ((t + 1) & 1) * BUFB, gt0 + t + 1, w, lane,
                 trig_b, valp_b, clog_b, wscore_b, live_b, cid_b,
                 ofire_b, ocan_b, ovalid_b, oshw_b, ocid_b);
      WAITCNT_VM(13);   // tile t landed; tile t+1's 13 DMAs stay in flight
    } else {
      WAITCNT_VM(0);    // tail: drain the last tile
    }

    // ---- read my fragments back from LDS (stride-16 = free 2-way aliasing)
    const int4   oc = *(const int4*)  (sb + W_OCID + lane * 16);
    const int4   cc = *(const int4*)  (sb + W_OCAN + lane * 16);
    const float4 ff = *(const float4*)(sb + W_OFIR + lane * 16);
    const float4 vv = *(const float4*)(sb + W_OVAL + lane * 16);
    const int4   cd = *(const int4*)  (sb + W_CID  + lane * 16);
    const int4   lm = *(const int4*)  (sb + W_LIVE + lane * 16);
    const float4 ph = *(const float4*)(sb + W_TRIG + lane * 16);
    const float4 pq = *(const float4*)(sb + W_VALP + lane * 16);
    const float4 lA = *(const float4*)(sb + W_CLOG + lane * 48 + 0);
    const float4 lB = *(const float4*)(sb + W_CLOG + lane * 48 + 16);
    const float4 lC = *(const float4*)(sb + W_CLOG + lane * 48 + 32);
    const float  wx = *(const float*) (sb + W_WSC + (tid >> 2) * 4);
    const float  wy = *(const float*) (sb + W_OSW + (tid >> 2) * 4);

    // ---- per-lane partial oracle table (my 4 slots, slot order)
    u64 tblLo = 0ull, tblHi = 0ull, fndLo = 0ull, fndHi = 0ull;
    {
      const int   ocs[4] = {oc.x, oc.y, oc.z, oc.w};
      const int   ccs[4] = {cc.x, cc.y, cc.z, cc.w};
      const float ffs[4] = {ff.x, ff.y, ff.z, ff.w};
      const float vvs[4] = {vv.x, vv.y, vv.z, vv.w};
      #pragma unroll
      for (int j = 0; j < 4; ++j) {
        const unsigned c  = (unsigned)ocs[j] & 31u;
        const unsigned sh = (c & 15u) * 4u;
        const bool isLo   = c < 16u;
        const bool seen   = (((isLo ? fndLo : fndHi) >> sh) & 1ull) != 0ull;
        const unsigned nib = (unsigned)ffs[j] | ((unsigned)vvs[j] << 1) |
                             ((unsigned)ccs[j] << 2);
        const u64 add  = seen ? 0ull : ((u64)nib << sh);
        const u64 fadd = 0xFull << sh;
        tblLo |= isLo ? add : 0ull;
        tblHi |= isLo ? 0ull : add;
        fndLo |= isLo ? fadd : 0ull;
        fndHi |= isLo ? 0ull : fadd;
      }
    }

    // ---- merge across the 4-lane row group (lower lane = earlier slot wins)
    #pragma unroll
    for (int m = 1; m <= 2; m <<= 1) {
      const u64 pTL = shflx64(tblLo, m);
      const u64 pTH = shflx64(tblHi, m);
      const u64 pFL = shflx64(fndLo, m);
      const u64 pFH = shflx64(fndHi, m);
      const bool iLow = (lane & m) == 0;
      const u64 loTL = iLow ? tblLo : pTL, hiTL = iLow ? pTL : tblLo;
      const u64 loTH = iLow ? tblHi : pTH, hiTH = iLow ? pTH : tblHi;
      const u64 loFL = iLow ? fndLo : pFL, hiFL = iLow ? pFL : fndLo;
      const u64 loFH = iLow ? fndHi : pFH, hiFH = iLow ? pFH : fndHi;
      tblLo = loTL | (hiTL & ~loFL);
      tblHi = loTH | (hiTH & ~loFH);
      fndLo = loFL | hiFL;
      fndHi = loFH | hiFH;
    }

    // ---- losses for my 4 slots (proven compute path, unchanged)
    {
      const int   cds[4] = {cd.x, cd.y, cd.z, cd.w};
      const int   lms[4] = {lm.x, lm.y, lm.z, lm.w};
      const float phs[4] = {ph.x, ph.y, ph.z, ph.w};
      const float pqs[4] = {pq.x, pq.y, pq.z, pq.w};
      const float L0[4] = {lA.x, lA.w, lB.z, lC.y};
      const float L1[4] = {lA.y, lB.x, lB.w, lC.z};
      const float L2[4] = {lA.z, lB.y, lC.x, lC.w};
      #pragma unroll
      for (int j = 0; j < 4; ++j) {
        const unsigned c  = (unsigned)cds[j] & 31u;
        const unsigned sh = (c & 15u) * 4u;
        const bool isLo   = c < 16u;
        const bool fnd = (c != 0u) &&
                         ((((isLo ? fndLo : fndHi) >> sh) & 1ull) != 0ull);
        unsigned nib = (unsigned)(((isLo ? tblLo : tblHi) >> sh)) & 15u;
        nib = fnd ? nib : 0u;
        const float fire_t = (float)(nib & 1u);
        const float val_t  = (float)((nib >> 1) & 1u);
        const int   can_t  = (int)(nib >> 2);

        const float m = lms[j] ? 1.f : 0.f;

        const float p  = fminf(fmaxf(phs[j], EPS_F), 1.f - EPS_F);
        const float bf = -__logf((fire_t != 0.f) ? p : 1.f - p);
        const float q  = fminf(fmaxf(pqs[j], EPS_F), 1.f - EPS_F);
        const float bv = -__logf((val_t != 0.f) ? q : 1.f - q);

        const float has = (can_t > 0 && lms[j]) ? 1.f : 0.f;
        const int tgt = (can_t - 1) < 0 ? 0 : (can_t - 1);
        const float l0 = L0[j], l1 = L1[j], l2 = L2[j];
        const float mx  = fmaxf(l0, fmaxf(l1, l2));
        const float lse = mx + __logf(__expf(l0 - mx) + __expf(l1 - mx) +
                                      __expf(l2 - mx));
        const float lt  = (tgt == 0) ? l0 : ((tgt == 1) ? l1 : l2);

        a0 += bf * m;
        a1 += m;
        a2 += (lse - lt) * has;
        a3 += has;
        a4 += bv * m;
      }
    }

    // ---- write term (one lane per row)
    if ((tid & 3) == 0) {
      a5 += fmaxf(wx, 0.f) - wx * wy + __logf(1.f + __expf(-fabsf(wx)));
    }
  }

  // ---- wave reduce, then block reduce via LDS (only barrier in the kernel)
  float v[6] = {a0, a1, a2, a3, a4, a5};
  #pragma unroll
  for (int off = 32; off > 0; off >>= 1) {
    #pragma unroll
    for (int i = 0; i < 6; ++i) v[i] += __shfl_down(v[i], off, 64);
  }
  __shared__ float red[4][6];
  if (lane == 0) {
    #pragma unroll
    for (int i = 0; i < 6; ++i) red[w][i] = v[i];
  }
  __syncthreads();
  if (tid == 0) {
    #pragma unroll
    for (int i = 0; i < 6; ++i)
      part[blockIdx.x * 6 + i] = red[0][i] + red[1][i] + red[2][i] + red[3][i];
  }
}

// Reduce NBLK partials in double, compute the 5 outputs.
__global__ __launch_bounds__(BLOCK) void loss_finalize(
    const float* __restrict__ part, float* __restrict__ out)
{
  double v[6] = {0, 0, 0, 0, 0, 0};
  for (int r = threadIdx.x; r < NBLK; r += BLOCK) {
    #pragma unroll
    for (int i = 0; i < 6; ++i) v[i] += (double)part[r * 6 + i];
  }
  #pragma unroll
  for (int off = 32; off > 0; off >>= 1) {
    #pragma unroll
    for (int i = 0; i < 6; ++i) v[i] += __shfl_down(v[i], off, 64);
  }
  __shared__ double red[4][6];
  const int w = threadIdx.x >> 6, lane = threadIdx.x & 63;
  if (lane == 0) {
    #pragma unroll
    for (int i = 0; i < 6; ++i) red[w][i] = v[i];
  }
  __syncthreads();
  if (threadIdx.x == 0) {
    double a[6];
    #pragma unroll
    for (int i = 0; i < 6; ++i) a[i] = red[0][i] + red[1][i] + red[2][i] + red[3][i];
    const double live_n = a[1] < 1.0 ? 1.0 : a[1];
    const double fire   = a[0] / live_n;                                   // LAM_FIRE   = 1.0
    const double cancel = (a[3] > 0.0) ? a[2] / (a[3] < 1.0 ? 1.0 : a[3])  // LAM_CANCEL = 1.0
                                       : 0.0;
    const double valid  = 0.5 * a[4] / live_n;                             // LAM_VALID  = 0.5
    const double wr     = 0.5 * a[5] / (double)ROWS;                       // LAM_WRITE  = 0.5
    out[0] = (float)fire;
    out[1] = (float)cancel;
    out[2] = (float)valid;
    out[3] = (float)wr;
    out[4] = (float)(fire + cancel + valid + wr);
  }
}

extern "C" void kernel_launch(void* const* d_in, const int* in_sizes, int n_in,
                              void* d_out, int out_size, void* d_ws, size_t ws_size,
                              hipStream_t stream) {
  const float* trig   = (const float*)d_in[0];
  const float* valp   = (const float*)d_in[1];
  const float* clog   = (const float*)d_in[2];
  const float* wscore = (const float*)d_in[3];
  const int*   live   = (const int*)  d_in[4];
  const int*   cid    = (const int*)  d_in[5];
  const float* ofire  = (const float*)d_in[6];
  const int*   ocan   = (const int*)  d_in[7];
  const float* ovalid = (const float*)d_in[8];
  const float* oshw   = (const float*)d_in[9];
  const int*   ocid   = (const int*)  d_in[10];
  float* out  = (float*)d_out;
  float* part = (float*)d_ws;   // NBLK*6 floats = 12 KB, fully overwritten

  loss_main<<<NBLK, BLOCK, 0, stream>>>(trig, valp, clog, wscore, live, cid,
                                        ofire, ocan, ovalid, oshw, ocid, part);
  loss_finalize<<<1, BLOCK, 0, stream>>>(part, out);
}